// Round 11
// baseline (195.592 us; speedup 1.0000x reference)
//
#include <hip/hip_runtime.h>
#include <hip/hip_bf16.h>

#define N_NODES 50000
#define N_EDGES 800000
#define D_IN    1024
#define D_OUT   256
#define CAP     64
#define LEAKY   0.01f

typedef __attribute__((ext_vector_type(8))) short bf16x8;
typedef __attribute__((ext_vector_type(4))) float f32x4;
typedef __attribute__((ext_vector_type(4))) int   i32x4;
typedef unsigned short u16;

__device__ __forceinline__ u16 f2bfu(float f) {
  uint32_t x = __float_as_uint(f);
  uint32_t r = (x + 0x7FFFu + ((x >> 16) & 1u)) >> 16;  // RNE
  return (u16)r;
}
__device__ __forceinline__ float bfu2f(u16 u) {
  return __uint_as_float(((uint32_t)u) << 16);
}

// ---------------------------------------------------------------------------
// Kernel 1: weight fp32 [1024][256] -> FRAGMENT-LINEAR bf16 image:
//   unit u (0..32767) = ((t*2 + wn)*8 + nf)*64 + lane, 16 B each, where
//   n = wn*128 + nf*16 + (lane&15), k = t*32 + (lane>>4)*8 .. +8.
// GEMM waves read one fragment as a single coalesced 1-KB burst (L2-hot).
// Also zeroes deg[].
// ---------------------------------------------------------------------------
__global__ __launch_bounds__(256) void wconv_kernel(const float* __restrict__ w,
                                                    char* __restrict__ wimg,
                                                    int* __restrict__ deg) {
  const int u = blockIdx.x * 256 + threadIdx.x;   // 0..32767
  if (u < N_NODES) deg[u] = 0;
  const int u2 = u + 32768;
  if (u2 < N_NODES) deg[u2] = 0;

  const int lane = u & 63;
  const int nf   = (u >> 6) & 7;
  const int wn   = (u >> 9) & 1;
  const int t    = u >> 10;
  const int n    = wn * 128 + nf * 16 + (lane & 15);
  const int k0   = t * 32 + (lane >> 4) * 8;
  bf16x8 v;
#pragma unroll
  for (int j = 0; j < 8; ++j) v[j] = (short)f2bfu(w[(size_t)(k0 + j) * D_OUT + n]);
  *(bf16x8*)(wimg + (size_t)u * 16) = v;   // consecutive u -> coalesced store
}

// ---------------------------------------------------------------------------
// Kernel 2 (FUSED): 60 build blocks + 391 GEMM blocks, 256 threads each.
// GEMM: NO LDS, NO BARRIERS. Each wave owns a 64m x 128n output tile
// (acc[8][4]); per k-step it loads 8 W fragments (1-KB coalesced bursts from
// the L2-resident image) and 4 X fragments DIRECTLY from fp32 x (per-lane
// fragment addressing; 16x128-B segments/instr), converts X in-register one
// fragment at a time, and issues 32 MFMA. X is double-buffered in fp32 regs
// (1-step slack); waves never reconverge, so their outstanding loads keep the
// memory queue continuously fed (the r1-r10 designs all burst-and-drained at
// barriers -> 20% memory duty cycle -> the invariant ~120 us).
// ---------------------------------------------------------------------------
#define MT_TILES ((N_NODES + 63) / 64)            // 782
#define GEMM_BLOCKS ((MT_TILES + 1) / 2)          // 391 (2 m-tiles per block)
#define BUILD_BLOCKS 60

__global__ __launch_bounds__(256) void gemm_build_kernel(
    const float* __restrict__ x, const char* __restrict__ wimg,
    u16* __restrict__ support,
    const int* __restrict__ ei, const float* __restrict__ ew,
    int* __restrict__ deg, int2* __restrict__ csr) {
  if (blockIdx.x < BUILD_BLOCKS) {
    const int t0 = blockIdx.x * 256 + threadIdx.x;
    for (int e = t0; e < N_EDGES; e += BUILD_BLOCKS * 256) {
      const int src = ei[e];
      const int dst = ei[N_EDGES + e];
      const float w = ew[e];
      const int slot = atomicAdd(&deg[dst], 1);
      if (slot < CAP) csr[dst * CAP + slot] = make_int2(src, __float_as_int(w));
    }
    return;
  }

  const int bi   = blockIdx.x - BUILD_BLOCKS;
  const int tid  = threadIdx.x;
  const int lane = tid & 63;
  const int wid  = tid >> 6;
  const int mt   = bi * 2 + (wid >> 1);   // m-tile (64 rows)
  const int wn   = wid & 1;               // n-half (128 cols)
  const int l15  = lane & 15;
  const int l16  = lane >> 4;

  // Per-mf X fragment base pointers (fp32). Row clamped for the ragged tail.
  const float* xptr[4];
#pragma unroll
  for (int mf = 0; mf < 4; ++mf) {
    int row = mt * 64 + mf * 16 + l15;
    row = min(row, N_NODES - 1);
    xptr[mf] = x + (size_t)row * D_IN + l16 * 8;
  }
  // W fragment base: wave reads 8 contiguous 1-KB bursts per k-step.
  const char* wbase = wimg + wn * 8192 + (size_t)lane * 16;

  f32x4 acc[8][4];
#pragma unroll
  for (int i = 0; i < 8; ++i)
#pragma unroll
    for (int j = 0; j < 4; ++j) acc[i][j] = (f32x4)0.0f;

  f32x4 r0[4][2], r1[4][2];   // rotating fp32 X sets (8 floats per frag)
  bf16x8 wf[8];

#define XFR(R, t) do {                                                     \
    _Pragma("unroll")                                                      \
    for (int mf_ = 0; mf_ < 4; ++mf_) {                                    \
      R[mf_][0] = *(const f32x4*)(xptr[mf_] + (t) * 32);                   \
      R[mf_][1] = *(const f32x4*)(xptr[mf_] + (t) * 32 + 4);               \
    }                                                                      \
  } while (0)

#define WFL(t) do {                                                        \
    _Pragma("unroll")                                                      \
    for (int nf_ = 0; nf_ < 8; ++nf_)                                      \
      wf[nf_] = *(const bf16x8*)(wbase + (size_t)(t) * 16384 + nf_ * 1024);\
  } while (0)

#define CVT_MFMA(R) do {                                                   \
    _Pragma("unroll")                                                      \
    for (int mf_ = 0; mf_ < 4; ++mf_) {                                    \
      bf16x8 xb_;                                                          \
      xb_[0] = (short)f2bfu(R[mf_][0][0]); xb_[1] = (short)f2bfu(R[mf_][0][1]); \
      xb_[2] = (short)f2bfu(R[mf_][0][2]); xb_[3] = (short)f2bfu(R[mf_][0][3]); \
      xb_[4] = (short)f2bfu(R[mf_][1][0]); xb_[5] = (short)f2bfu(R[mf_][1][1]); \
      xb_[6] = (short)f2bfu(R[mf_][1][2]); xb_[7] = (short)f2bfu(R[mf_][1][3]); \
      _Pragma("unroll")                                                    \
      for (int nf_ = 0; nf_ < 8; ++nf_)                                    \
        acc[nf_][mf_] = __builtin_amdgcn_mfma_f32_16x16x32_bf16(           \
            wf[nf_], xb_, acc[nf_][mf_], 0, 0, 0);                         \
    }                                                                      \
  } while (0)

  XFR(r0, 0);
  for (int t = 0; t < 32; t += 2) {
    WFL(t);
    XFR(r1, t + 1);                       // t+1 <= 31 always
    CVT_MFMA(r0);                         // r0 loaded one half-step ago
    WFL(t + 1);
    XFR(r0, min(t + 2, 31));              // clamp: final reload unused
    CVT_MFMA(r1);
  }

#undef XFR
#undef WFL
#undef CVT_MFMA

  // D: m = mt*64 + mf*16 + l15, n = wn*128 + nf*16 + l16*4 + reg.
#pragma unroll
  for (int mf = 0; mf < 4; ++mf) {
    const int m = mt * 64 + mf * 16 + l15;
    if (m < N_NODES) {
#pragma unroll
      for (int nf = 0; nf < 8; ++nf) {
        const int n = wn * 128 + nf * 16 + l16 * 4;
        ushort4 o;
        o.x = f2bfu(acc[nf][mf][0]);
        o.y = f2bfu(acc[nf][mf][1]);
        o.z = f2bfu(acc[nf][mf][2]);
        o.w = f2bfu(acc[nf][mf][3]);
        *(ushort4*)&support[(size_t)m * D_OUT + n] = o;
      }
    }
  }
}

// ---------------------------------------------------------------------------
// Kernel 3: per-node gather-aggregate + epilogue (r5 version, ~20 us).
// ---------------------------------------------------------------------------
__global__ __launch_bounds__(256) void agg_kernel(const u16* __restrict__ support,
                                                  const int* __restrict__ deg,
                                                  const int2* __restrict__ csr,
                                                  const float* __restrict__ norm,
                                                  const float* __restrict__ bias,
                                                  float* __restrict__ out) {
  const int lane = threadIdx.x & 63;
  const int wid  = threadIdx.x >> 6;
  const int node = blockIdx.x * 4 + wid;   // grid 12500 -> exactly 50000
  const int d    = min(deg[node], CAP);
  const int cb   = node * CAP;
  const int ch   = lane * 4;

  float a0 = 0.f, a1 = 0.f, a2 = 0.f, a3 = 0.f;
  int s = 0;

  for (; s + 16 <= d; s += 16) {
    i32x4 q[8];
#pragma unroll
    for (int i = 0; i < 8; ++i)
      q[i] = __builtin_nontemporal_load((const i32x4*)&csr[cb + s + 2 * i]);
    ushort4 v[16];
#pragma unroll
    for (int i = 0; i < 8; ++i) {
      v[2 * i]     = *(const ushort4*)&support[(size_t)q[i][0] * D_OUT + ch];
      v[2 * i + 1] = *(const ushort4*)&support[(size_t)q[i][2] * D_OUT + ch];
    }
#pragma unroll
    for (int i = 0; i < 8; ++i) {
      const float wa = __int_as_float(q[i][1]);
      const float wb = __int_as_float(q[i][3]);
      a0 = fmaf(wa, bfu2f(v[2 * i].x), a0);
      a1 = fmaf(wa, bfu2f(v[2 * i].y), a1);
      a2 = fmaf(wa, bfu2f(v[2 * i].z), a2);
      a3 = fmaf(wa, bfu2f(v[2 * i].w), a3);
      a0 = fmaf(wb, bfu2f(v[2 * i + 1].x), a0);
      a1 = fmaf(wb, bfu2f(v[2 * i + 1].y), a1);
      a2 = fmaf(wb, bfu2f(v[2 * i + 1].z), a2);
      a3 = fmaf(wb, bfu2f(v[2 * i + 1].w), a3);
    }
  }

  for (; s + 8 <= d; s += 8) {
    i32x4 q[4];
#pragma unroll
    for (int i = 0; i < 4; ++i)
      q[i] = __builtin_nontemporal_load((const i32x4*)&csr[cb + s + 2 * i]);
    ushort4 v[8];
#pragma unroll
    for (int i = 0; i < 4; ++i) {
      v[2 * i]     = *(const ushort4*)&support[(size_t)q[i][0] * D_OUT + ch];
      v[2 * i + 1] = *(const ushort4*)&support[(size_t)q[i][2] * D_OUT + ch];
    }
#pragma unroll
    for (int i = 0; i < 4; ++i) {
      const float wa = __int_as_float(q[i][1]);
      const float wb = __int_as_float(q[i][3]);
      a0 = fmaf(wa, bfu2f(v[2 * i].x), a0);
      a1 = fmaf(wa, bfu2f(v[2 * i].y), a1);
      a2 = fmaf(wa, bfu2f(v[2 * i].z), a2);
      a3 = fmaf(wa, bfu2f(v[2 * i].w), a3);
      a0 = fmaf(wb, bfu2f(v[2 * i + 1].x), a0);
      a1 = fmaf(wb, bfu2f(v[2 * i + 1].y), a1);
      a2 = fmaf(wb, bfu2f(v[2 * i + 1].z), a2);
      a3 = fmaf(wb, bfu2f(v[2 * i + 1].w), a3);
    }
  }

  for (; s < d; ++s) {
    const int2  e   = csr[cb + s];
    const float wgt = __int_as_float(e.y);
    const ushort4 v = *(const ushort4*)&support[(size_t)e.x * D_OUT + ch];
    a0 = fmaf(wgt, bfu2f(v.x), a0);
    a1 = fmaf(wgt, bfu2f(v.y), a1);
    a2 = fmaf(wgt, bfu2f(v.z), a2);
    a3 = fmaf(wgt, bfu2f(v.w), a3);
  }

  const float rn = 1.0f / norm[node];
  const float4 b = *(const float4*)&bias[ch];
  float o0 = fmaf(a0, rn, b.x);
  float o1 = fmaf(a1, rn, b.y);
  float o2 = fmaf(a2, rn, b.z);
  float o3 = fmaf(a3, rn, b.w);
  o0 = o0 > 0.f ? o0 : o0 * LEAKY;
  o1 = o1 > 0.f ? o1 : o1 * LEAKY;
  o2 = o2 > 0.f ? o2 : o2 * LEAKY;
  o3 = o3 > 0.f ? o3 : o3 * LEAKY;
  f32x4 ov;
  ov[0] = o0; ov[1] = o1; ov[2] = o2; ov[3] = o3;
  __builtin_nontemporal_store(ov, (f32x4*)&out[(size_t)node * D_OUT + ch]);
}

// ---------------------------------------------------------------------------
// ws layout (bytes):
//   support  bf16  [50000][256]      @ 0          25,600,000
//   Wimg     bf16  frag-linear       @ 25,600,000    524,288
//   csr      int2  [50000][64]       @ 26,124,288 25,600,000
//   deg      int   [50000]           @ 51,724,288    200,000
// ---------------------------------------------------------------------------
extern "C" void kernel_launch(void* const* d_in, const int* in_sizes, int n_in,
                              void* d_out, int out_size, void* d_ws, size_t ws_size,
                              hipStream_t stream) {
  const float* x    = (const float*)d_in[0];
  const float* w    = (const float*)d_in[1];
  const float* bias = (const float*)d_in[2];
  const int*   ei   = (const int*)d_in[3];
  const float* ew   = (const float*)d_in[4];
  const float* norm = (const float*)d_in[5];
  float* out = (float*)d_out;

  char* ws = (char*)d_ws;
  u16*   support = (u16*)  (ws);
  char*  wimg    =         (ws + 25600000);
  int2*  csr     = (int2*) (ws + 26124288);
  int*   deg     = (int*)  (ws + 51724288);

  wconv_kernel<<<128, 256, 0, stream>>>(w, wimg, deg);
  gemm_build_kernel<<<BUILD_BLOCKS + GEMM_BLOCKS, 256, 0, stream>>>(
      x, wimg, support, ei, ew, deg, csr);
  agg_kernel<<<N_NODES / 4, 256, 0, stream>>>(support, deg, csr, norm, bias, out);
}